// Round 5
// baseline (669.986 us; speedup 1.0000x reference)
//
#include <hip/hip_runtime.h>
#include <math.h>

#define SLOPE  0.2f
#define NB     32
#define LEN    512
#define LATENT 64
#define HID    64
#define IN_DIM 129
#define TROWS  514
#define NTOT   (NB * LEN)      // 16384

typedef __attribute__((ext_vector_type(8)))  short bf16x8;
typedef __attribute__((ext_vector_type(16))) float f32x16;
typedef __attribute__((ext_vector_type(4)))  float f32x4;

struct alignas(8) US4 { unsigned short x, y, z, w; };

// round-to-nearest bf16 split: v = hi + lo + O(2^-18 v)
__device__ inline void bsplit(float v, unsigned short& hi, unsigned short& lo) {
    unsigned int u  = __builtin_bit_cast(unsigned int, v);
    unsigned int hb = (u + 0x7fffu + ((u >> 16) & 1u)) >> 16;
    hi = (unsigned short)hb;
    float fh = __builtin_bit_cast(float, hb << 16);
    float r  = v - fh;                      // exact (Sterbenz)
    unsigned int u2 = __builtin_bit_cast(unsigned int, r);
    lo = (unsigned short)((u2 + 0x7fffu + ((u2 >> 16) & 1u)) >> 16);
}

// pre-pass: W1[:, :, :128] -> fragment-major bf16 hi/lo W1f[l][i][ks][part][lane][8]
//           W1[:, :, 128]  -> W1t fp32 ; also zero out_lad
__global__ __launch_bounds__(256)
void conv_w1(const float* __restrict__ W1g, unsigned short* __restrict__ W1f,
             float* __restrict__ W1t, float* __restrict__ out_lad) {
    const int idx = blockIdx.x * 256 + threadIdx.x;   // 0..65535
    if (idx < NTOT) out_lad[idx] = 0.f;
    const int row  = idx >> 4;                        // 0..4095 = l*64 + h
    const int o    = idx & 15;                        // k-octet, k = 8*o
    const int ks   = o >> 1, hi32 = o & 1;
    const int l    = row >> 6, h = row & 63;
    const int i    = h >> 5,  r32 = h & 31;
    const int lane = hi32 * 32 + r32;
    const float* src = W1g + (size_t)row * IN_DIM + o * 8;
    unsigned short hh[8], ll[8];
    #pragma unroll
    for (int e = 0; e < 8; ++e) bsplit(src[e], hh[e], ll[e]);
    // strides (ushorts): l=16384, i=8192, ks=1024, part=512, lane=8
    const size_t base = (size_t)l * 16384 + (size_t)i * 8192 + (size_t)ks * 1024
                      + (size_t)lane * 8;
    *reinterpret_cast<US4*>(W1f + base)       = US4{hh[0], hh[1], hh[2], hh[3]};
    *reinterpret_cast<US4*>(W1f + base + 4)   = US4{hh[4], hh[5], hh[6], hh[7]};
    *reinterpret_cast<US4*>(W1f + base + 512) = US4{ll[0], ll[1], ll[2], ll[3]};
    *reinterpret_cast<US4*>(W1f + base + 516) = US4{ll[4], ll[5], ll[6], ll[7]};
    if (o == 15) W1t[row] = src[8];               // element k=128
}

// block: 64 n-rows x 4 latents (1 wave per latent). wave tile: 64h x 64n.
__global__ __launch_bounds__(256, 6)
void fused_mfma(const float* __restrict__ xg,
                const float* __restrict__ b1g, const float* __restrict__ W2g,
                const float* __restrict__ b2g,
                const unsigned short* __restrict__ W1f,
                const float* __restrict__ W1t,
                float* __restrict__ out_res, float* __restrict__ out_lad)
{
    __shared__ unsigned short sXh[66][72];   // x hi, stride 144B (16B-aligned)
    __shared__ unsigned short sXl[66][72];   // x lo
    __shared__ float sXt[66][4];             // fp32 xt columns (4 l's)
    __shared__ float sJ[64][4];              // per-l jacobians

    const int tid = threadIdx.x;
    const int bx  = blockIdx.x;              // 0..255 : 64-row M tile
    const int by  = blockIdx.y;              // 0..15  : 4 latents
    const int bb  = bx >> 3;
    const int t0  = (bx & 7) * 64;
    const float* xbase = xg + ((size_t)bb * TROWS + t0) * LATENT;

    // ---- stage x tile: 66 rows x 64, bf16 hi/lo + fp32 xt columns ----
    for (int i = tid; i < 66 * 16; i += 256) {
        const int row = i >> 4, c4 = (i & 15) << 2;
        const float4 v = *reinterpret_cast<const float4*>(xbase + row * LATENT + c4);
        unsigned short h0,h1,h2,h3, l0,l1,l2,l3;
        bsplit(v.x, h0, l0); bsplit(v.y, h1, l1);
        bsplit(v.z, h2, l2); bsplit(v.w, h3, l3);
        *reinterpret_cast<US4*>(&sXh[row][c4]) = US4{h0, h1, h2, h3};
        *reinterpret_cast<US4*>(&sXl[row][c4]) = US4{l0, l1, l2, l3};
    }
    for (int i = tid; i < 66 * 4; i += 256) {
        const int row = i >> 2, w = i & 3;
        sXt[row][w] = xbase[row * LATENT + by * 4 + w];
    }
    __syncthreads();

    const int wn   = tid >> 6;               // 0..3 : which latent
    const int lane = tid & 63;
    const int r32  = lane & 31;
    const int hi32 = lane >> 5;
    const int l    = by * 4 + wn;

    // ---- acc init = b1 (C/D row h = i*32 + 4*hi32 + 8*g + m) ----
    f32x16 acc[2][2];
    #pragma unroll
    for (int i = 0; i < 2; ++i)
        #pragma unroll
        for (int g = 0; g < 4; ++g) {
            const f32x4 b14 = *reinterpret_cast<const f32x4*>(
                b1g + l * HID + i * 32 + hi32 * 4 + g * 8);
            #pragma unroll
            for (int m = 0; m < 4; ++m) {
                acc[i][0][g * 4 + m] = b14[m];
                acc[i][1][g * 4 + m] = b14[m];
            }
        }

    // ---- K loop: A = W1 fragments (coalesced global), B = x rows (LDS) ----
    const unsigned short* A0 = W1f + (size_t)l * 16384 + (size_t)lane * 8;

    #pragma unroll
    for (int ks = 0; ks < 8; ++ks) {
        const int lag = ks >> 2;                    // which lag block of x
        const int cc  = (ks & 3) * 16 + hi32 * 8;   // column within lag block
        bf16x8 awh[2], awl[2], bxh[2], bxl[2];
        #pragma unroll
        for (int i = 0; i < 2; ++i) {
            const unsigned short* p = A0 + i * 8192 + ks * 1024;
            awh[i] = *reinterpret_cast<const bf16x8*>(p);
            awl[i] = *reinterpret_cast<const bf16x8*>(p + 512);
        }
        #pragma unroll
        for (int j = 0; j < 2; ++j) {
            const int rr = j * 32 + r32 + lag;
            bxh[j] = *reinterpret_cast<const bf16x8*>(&sXh[rr][cc]);
            bxl[j] = *reinterpret_cast<const bf16x8*>(&sXl[rr][cc]);
        }
        #pragma unroll
        for (int i = 0; i < 2; ++i)
            #pragma unroll
            for (int j = 0; j < 2; ++j) {
                acc[i][j] = __builtin_amdgcn_mfma_f32_32x32x16_bf16(awh[i], bxh[j], acc[i][j], 0, 0, 0);
                acc[i][j] = __builtin_amdgcn_mfma_f32_32x32x16_bf16(awh[i], bxl[j], acc[i][j], 0, 0, 0);
                acc[i][j] = __builtin_amdgcn_mfma_f32_32x32x16_bf16(awl[i], bxh[j], acc[i][j], 0, 0, 0);
            }
    }

    // ---- fused epilogue: h lives in (i, reg, hi32); n = j*32 + r32 ----
    const float xt0 = sXt[r32 + 2][wn];
    const float xt1 = sXt[32 + r32 + 2][wn];
    float res0 = 0.f, res1 = 0.f, jp0 = 0.f, jp1 = 0.f, jc = 0.f;

    #pragma unroll
    for (int i = 0; i < 2; ++i)
        #pragma unroll
        for (int g = 0; g < 4; ++g) {
            const int h0 = l * HID + i * 32 + hi32 * 4 + g * 8;
            const f32x4 wt = *reinterpret_cast<const f32x4*>(W1t + h0);
            const f32x4 w2 = *reinterpret_cast<const f32x4*>(W2g + h0);
            #pragma unroll
            for (int m = 0; m < 4; ++m) {
                const float c0 = w2[m] * wt[m];
                jc += c0;
                const int r = g * 4 + m;
                const float pre0 = fmaf(xt0, wt[m], acc[i][0][r]);
                const float pre1 = fmaf(xt1, wt[m], acc[i][1][r]);
                res0 += w2[m] * fmaxf(pre0, SLOPE * pre0);
                res1 += w2[m] * fmaxf(pre1, SLOPE * pre1);
                jp0 += (pre0 >= 0.f) ? c0 : 0.f;
                jp1 += (pre1 >= 0.f) ? c0 : 0.f;
            }
        }

    res0 += __shfl_xor(res0, 32);
    res1 += __shfl_xor(res1, 32);
    jp0  += __shfl_xor(jp0, 32);
    jp1  += __shfl_xor(jp1, 32);
    jc   += __shfl_xor(jc, 32);
    const float jac0 = SLOPE * jc + (1.f - SLOPE) * jp0;
    const float jac1 = SLOPE * jc + (1.f - SLOPE) * jp1;

    if (hi32 == 0) {
        const float b2v = b2g[l];
        const size_t n0 = (size_t)bx * 64 + r32;
        out_res[n0 * LATENT + l]        = res0 + b2v;
        out_res[(n0 + 32) * LATENT + l] = res1 + b2v;
        sJ[r32][wn]      = jac0;
        sJ[r32 + 32][wn] = jac1;
    }
    __syncthreads();
    if (tid < 64) {
        const float p = sJ[tid][0] * sJ[tid][1] * sJ[tid][2] * sJ[tid][3];
        atomicAdd(&out_lad[bx * 64 + tid], logf(fabsf(p)));
    }
}

extern "C" void kernel_launch(void* const* d_in, const int* in_sizes, int n_in,
                              void* d_out, int out_size, void* d_ws, size_t ws_size,
                              hipStream_t stream) {
    const float* xg  = (const float*)d_in[0];
    const float* W1g = (const float*)d_in[1];
    const float* b1g = (const float*)d_in[2];
    const float* W2g = (const float*)d_in[3];
    const float* b2g = (const float*)d_in[4];

    float* out_res = (float*)d_out;
    float* out_lad = out_res + (size_t)NTOT * LATENT;

    float*          W1t = (float*)d_ws;                   // 16 KB
    unsigned short* W1f = (unsigned short*)(W1t + 4096);  // 2 MB fragment-major

    conv_w1<<<256, 256, 0, stream>>>(W1g, W1f, W1t, out_lad);

    dim3 grid(256, 16);  // (64-row n-tiles, latent quads)
    fused_mfma<<<grid, 256, 0, stream>>>(xg, b1g, W2g, b2g, W1f, W1t,
                                         out_res, out_lad);
}

// Round 7
// 149.438 us; speedup vs baseline: 4.4834x; 4.4834x over previous
//
#include <hip/hip_runtime.h>
#include <math.h>

#define SLOPE  0.2f
#define NB     32
#define LEN    512
#define LATENT 64
#define HID    64
#define IN_DIM 129
#define TROWS  514
#define NTOT   (NB * LEN)      // 16384

typedef __attribute__((ext_vector_type(8)))  short bf16x8;
typedef __attribute__((ext_vector_type(16))) float f32x16;
typedef __attribute__((ext_vector_type(4)))  float f32x4;

struct alignas(8) US4 { unsigned short x, y, z, w; };

// round-to-nearest bf16 split: v = hi + lo + O(2^-18 v)
__device__ inline void bsplit(float v, unsigned short& hi, unsigned short& lo) {
    unsigned int u  = __builtin_bit_cast(unsigned int, v);
    unsigned int hb = (u + 0x7fffu + ((u >> 16) & 1u)) >> 16;
    hi = (unsigned short)hb;
    float fh = __builtin_bit_cast(float, hb << 16);
    float r  = v - fh;                      // exact (Sterbenz)
    unsigned int u2 = __builtin_bit_cast(unsigned int, r);
    lo = (unsigned short)((u2 + 0x7fffu + ((u2 >> 16) & 1u)) >> 16);
}

// pre-pass: W1[:, :, :128] -> fragment-major bf16 hi/lo W1f[l][i][ks][part][lane][8]
//           W1[:, :, 128]  -> W1t fp32 ; also zero out_lad   (ws use: 2.02 MB, proven)
__global__ __launch_bounds__(256)
void conv_w1(const float* __restrict__ W1g, unsigned short* __restrict__ W1f,
             float* __restrict__ W1t, float* __restrict__ out_lad) {
    const int idx = blockIdx.x * 256 + threadIdx.x;   // 0..65535
    if (idx < NTOT) out_lad[idx] = 0.f;
    const int row  = idx >> 4;                        // 0..4095 = l*64 + h
    const int o    = idx & 15;                        // k-octet, k = 8*o
    const int ks   = o >> 1, hi32 = o & 1;
    const int l    = row >> 6, h = row & 63;
    const int i    = h >> 5,  r32 = h & 31;
    const int lane = hi32 * 32 + r32;
    const float* src = W1g + (size_t)row * IN_DIM + o * 8;
    unsigned short hh[8], ll[8];
    #pragma unroll
    for (int e = 0; e < 8; ++e) bsplit(src[e], hh[e], ll[e]);
    // strides (ushorts): l=16384, i=8192, ks=1024, part=512, lane=8
    const size_t base = (size_t)l * 16384 + (size_t)i * 8192 + (size_t)ks * 1024
                      + (size_t)lane * 8;
    *reinterpret_cast<US4*>(W1f + base)       = US4{hh[0], hh[1], hh[2], hh[3]};
    *reinterpret_cast<US4*>(W1f + base + 4)   = US4{hh[4], hh[5], hh[6], hh[7]};
    *reinterpret_cast<US4*>(W1f + base + 512) = US4{ll[0], ll[1], ll[2], ll[3]};
    *reinterpret_cast<US4*>(W1f + base + 516) = US4{ll[4], ll[5], ll[6], ll[7]};
    if (o == 15) W1t[row] = src[8];               // element k=128
}

// weight-stationary persistent block: 512 threads = 8 waves = 8 latents,
// W1 fragments held in registers; loops over the 8 n-tiles of one batch row.
__global__ __launch_bounds__(512, 2)
void fused_mfma(const float* __restrict__ xg,
                const float* __restrict__ b1g, const float* __restrict__ W2g,
                const float* __restrict__ b2g,
                const unsigned short* __restrict__ W1f,
                const float* __restrict__ W1t,
                float* __restrict__ out_res, float* __restrict__ out_lad)
{
    __shared__ unsigned short sXh[66][72];   // x hi, stride 144B (16B-aligned)
    __shared__ unsigned short sXl[66][72];   // x lo
    __shared__ float sXt[66][8];             // fp32 xt columns (8 l's)
    __shared__ float sJ[64][8];              // per-l jacobians

    const int tid  = threadIdx.x;
    const int by   = blockIdx.x & 7;         // latent oct
    const int pt   = blockIdx.x >> 3;        // batch row 0..31
    const int wn   = tid >> 6;               // 0..7 : which latent
    const int lane = tid & 63;
    const int r32  = lane & 31;
    const int hi32 = lane >> 5;
    const int l    = by * 8 + wn;

    // ---- load W1 fragments once into registers (32 x bf16x8 = 128 VGPR) ----
    const unsigned short* A0 = W1f + (size_t)l * 16384 + (size_t)lane * 8;
    bf16x8 awh[2][8], awl[2][8];
    #pragma unroll
    for (int i = 0; i < 2; ++i)
        #pragma unroll
        for (int ks = 0; ks < 8; ++ks) {
            const unsigned short* p = A0 + i * 8192 + ks * 1024;
            awh[i][ks] = *reinterpret_cast<const bf16x8*>(p);
            awl[i][ks] = *reinterpret_cast<const bf16x8*>(p + 512);
        }

    #pragma unroll 1
    for (int s = 0; s < 8; ++s) {
        const size_t xrow0 = (size_t)pt * TROWS + s * 64;

        // ---- stage x tile: 66 rows x 64, bf16 hi/lo + fp32 xt columns ----
        for (int i = tid; i < 66 * 16; i += 512) {
            const int row = i >> 4, c4 = (i & 15) << 2;
            const float4 v = *reinterpret_cast<const float4*>(
                xg + (xrow0 + row) * LATENT + c4);
            unsigned short h0,h1,h2,h3, l0,l1,l2,l3;
            bsplit(v.x, h0, l0); bsplit(v.y, h1, l1);
            bsplit(v.z, h2, l2); bsplit(v.w, h3, l3);
            *reinterpret_cast<US4*>(&sXh[row][c4]) = US4{h0, h1, h2, h3};
            *reinterpret_cast<US4*>(&sXl[row][c4]) = US4{l0, l1, l2, l3};
        }
        for (int i = tid; i < 66 * 8; i += 512) {
            const int row = i >> 3, w = i & 7;
            sXt[row][w] = xg[(xrow0 + row) * LATENT + by * 8 + w];
        }
        __syncthreads();

        // ---- acc init = b1 (C/D row h = i*32 + 4*hi32 + 8*g + m) ----
        f32x16 acc[2][2];
        #pragma unroll
        for (int i = 0; i < 2; ++i)
            #pragma unroll
            for (int g = 0; g < 4; ++g) {
                const f32x4 b14 = *reinterpret_cast<const f32x4*>(
                    b1g + l * HID + i * 32 + hi32 * 4 + g * 8);
                #pragma unroll
                for (int m = 0; m < 4; ++m) {
                    acc[i][0][g * 4 + m] = b14[m];
                    acc[i][1][g * 4 + m] = b14[m];
                }
            }

        // ---- K loop: A = W1 regs, B = x rows (LDS) — no global loads ----
        #pragma unroll
        for (int ks = 0; ks < 8; ++ks) {
            const int lag = ks >> 2;
            const int cc  = (ks & 3) * 16 + hi32 * 8;
            bf16x8 bxh[2], bxl[2];
            #pragma unroll
            for (int j = 0; j < 2; ++j) {
                const int rr = j * 32 + r32 + lag;
                bxh[j] = *reinterpret_cast<const bf16x8*>(&sXh[rr][cc]);
                bxl[j] = *reinterpret_cast<const bf16x8*>(&sXl[rr][cc]);
            }
            #pragma unroll
            for (int i = 0; i < 2; ++i)
                #pragma unroll
                for (int j = 0; j < 2; ++j) {
                    acc[i][j] = __builtin_amdgcn_mfma_f32_32x32x16_bf16(awh[i][ks], bxh[j], acc[i][j], 0, 0, 0);
                    acc[i][j] = __builtin_amdgcn_mfma_f32_32x32x16_bf16(awh[i][ks], bxl[j], acc[i][j], 0, 0, 0);
                    acc[i][j] = __builtin_amdgcn_mfma_f32_32x32x16_bf16(awl[i][ks], bxh[j], acc[i][j], 0, 0, 0);
                }
        }

        // ---- fused epilogue: h in (i, reg, hi32); n = j*32 + r32 ----
        const float xt0 = sXt[r32 + 2][wn];
        const float xt1 = sXt[32 + r32 + 2][wn];
        float res0 = 0.f, res1 = 0.f, jp0 = 0.f, jp1 = 0.f, jc = 0.f;

        #pragma unroll
        for (int i = 0; i < 2; ++i)
            #pragma unroll
            for (int g = 0; g < 4; ++g) {
                const int h0 = l * HID + i * 32 + hi32 * 4 + g * 8;
                const f32x4 wt = *reinterpret_cast<const f32x4*>(W1t + h0);
                const f32x4 w2 = *reinterpret_cast<const f32x4*>(W2g + h0);
                #pragma unroll
                for (int m = 0; m < 4; ++m) {
                    const float c0 = w2[m] * wt[m];
                    jc += c0;
                    const int r = g * 4 + m;
                    const float pre0 = fmaf(xt0, wt[m], acc[i][0][r]);
                    const float pre1 = fmaf(xt1, wt[m], acc[i][1][r]);
                    res0 += w2[m] * fmaxf(pre0, SLOPE * pre0);
                    res1 += w2[m] * fmaxf(pre1, SLOPE * pre1);
                    jp0 += (pre0 >= 0.f) ? c0 : 0.f;
                    jp1 += (pre1 >= 0.f) ? c0 : 0.f;
                }
            }

        res0 += __shfl_xor(res0, 32);
        res1 += __shfl_xor(res1, 32);
        jp0  += __shfl_xor(jp0, 32);
        jp1  += __shfl_xor(jp1, 32);
        jc   += __shfl_xor(jc, 32);
        const float jac0 = SLOPE * jc + (1.f - SLOPE) * jp0;
        const float jac1 = SLOPE * jc + (1.f - SLOPE) * jp1;

        const size_t nbase = (size_t)pt * LEN + s * 64;
        if (hi32 == 0) {
            const float b2v = b2g[l];
            const size_t n0 = nbase + r32;
            out_res[n0 * LATENT + l]        = res0 + b2v;
            out_res[(n0 + 32) * LATENT + l] = res1 + b2v;
            sJ[r32][wn]      = jac0;
            sJ[r32 + 32][wn] = jac1;
        }
        __syncthreads();
        if (tid < 64) {
            const float p = sJ[tid][0] * sJ[tid][1] * sJ[tid][2] * sJ[tid][3]
                          * sJ[tid][4] * sJ[tid][5] * sJ[tid][6] * sJ[tid][7];
            atomicAdd(&out_lad[nbase + tid], logf(fabsf(p)));
        }
        __syncthreads();   // protect LDS before next tile's staging
    }
}

extern "C" void kernel_launch(void* const* d_in, const int* in_sizes, int n_in,
                              void* d_out, int out_size, void* d_ws, size_t ws_size,
                              hipStream_t stream) {
    const float* xg  = (const float*)d_in[0];
    const float* W1g = (const float*)d_in[1];
    const float* b1g = (const float*)d_in[2];
    const float* W2g = (const float*)d_in[3];
    const float* b2g = (const float*)d_in[4];

    float* out_res = (float*)d_out;
    float* out_lad = out_res + (size_t)NTOT * LATENT;

    float*          W1t = (float*)d_ws;                   // 16 KB
    unsigned short* W1f = (unsigned short*)(W1t + 4096);  // 2 MB fragment-major

    conv_w1<<<256, 256, 0, stream>>>(W1g, W1f, W1t, out_lad);

    dim3 grid(256);  // (8 latent octs) x (32 batch rows) = 1 block per CU
    fused_mfma<<<grid, 512, 0, stream>>>(xg, b1g, W2g, b2g, W1f, W1t,
                                         out_res, out_lad);
}